// Round 2
// baseline (303.202 us; speedup 1.0000x reference)
//
#include <hip/hip_runtime.h>
#include <stdint.h>

// LATENT=128, HIDDEN=2048, N_PARTS=128, K=2048
// outputs: omega(1152,2048) transf(1536,2048) rot(1152,2048) transl(384,2048)

typedef short bf16x8 __attribute__((ext_vector_type(8)));
typedef float f32x4 __attribute__((ext_vector_type(4)));

__device__ __forceinline__ unsigned short f2bf(float f) {
  unsigned int x = __float_as_uint(f);
  unsigned int r = (x + 0x7fffu + ((x >> 16) & 1u)) >> 16;
  return (unsigned short)r;
}

__device__ __forceinline__ void gld_lds16(const void* g, void* l) {
  __builtin_amdgcn_global_load_lds(
      (__attribute__((address_space(1))) void*)(g),
      (__attribute__((address_space(3))) void*)(l),
      16, 0, 0);
}

// ---------------------------------------------------------------------------
// Weight fp32 -> bf16 cast (all 8 weights, one pass). Segment offsets in elems:
__global__ void cast_weights_k(const float* __restrict__ wo0, const float* __restrict__ wo1,
                               const float* __restrict__ wo2, const float* __restrict__ wo3,
                               const float* __restrict__ wt0, const float* __restrict__ wt1,
                               const float* __restrict__ wt2, const float* __restrict__ wt3,
                               unsigned short* __restrict__ dst) {
  int gid = blockIdx.x * 256 + threadIdx.x;
  int idx = gid * 4;
  if (idx >= 20447232) return;
  const float* src;
  int off;
  if (idx < 8650752) {
    if (idx < 262144)       { src = wo0; off = idx; }
    else if (idx < 4456448) { src = wo1; off = idx - 262144; }
    else                    { src = wo2; off = idx - 4456448; }
  } else {
    if (idx < 11010048)      { src = wo3; off = idx - 8650752; }
    else if (idx < 11272192) { src = wt0; off = idx - 11010048; }
    else if (idx < 15466496) { src = wt1; off = idx - 11272192; }
    else if (idx < 19660800) { src = wt2; off = idx - 15466496; }
    else                     { src = wt3; off = idx - 19660800; }
  }
  float4 v = *(const float4*)(src + off);
  ushort4 o;
  o.x = f2bf(v.x); o.y = f2bf(v.y); o.z = f2bf(v.z); o.w = f2bf(v.w);
  *(ushort4*)(dst + idx) = o;
}

// ---------------------------------------------------------------------------
// x (128 x 2048) fp32 -> Xt (2048 x 128) bf16
__global__ void transpose_cast_k(const float* __restrict__ x, unsigned short* __restrict__ xt) {
  __shared__ float tile[32][33];
  const int bx = blockIdx.x, by = blockIdx.y;
  const int tx = threadIdx.x, ty = threadIdx.y;
#pragma unroll
  for (int i = 0; i < 32; i += 8)
    tile[ty + i][tx] = x[(size_t)(by * 32 + ty + i) * 2048 + bx * 32 + tx];
  __syncthreads();
#pragma unroll
  for (int i = 0; i < 32; i += 8)
    xt[(size_t)(bx * 32 + ty + i) * 128 + by * 32 + tx] = f2bf(tile[tx][ty + i]);
}

// ---------------------------------------------------------------------------
// TN GEMM: C(M x N) = A(M x K) * B(N x K)^T, bf16 in, fp32 acc.
// Tile 64(M) x 128(N), BK=32, 256 threads = 4 waves in 2x2, wave tile 32x64.
// Two independent problems fused via blockIdx.y; split-K via blockIdx.z
// (MODE 1 only; partial written at C + z*csplit_bytes).
// LDS XOR swizzle: phys_seg = seg ^ ((row>>1)&3); staging permutes the global
// source per lane so LDS dests stay lane-contiguous (global_load_lds-legal),
// and each 16-lane read phase hits every 4-bank group exactly twice (free).
// MODE 0: relu + bf16 out.  MODE 1: fp32 out, no relu.
template <int MODE>
__global__ __launch_bounds__(256, 4) void gemm_tn(
    const unsigned short* __restrict__ A0, const unsigned short* __restrict__ B0,
    void* __restrict__ C0v, int n0tiles, int ldc0, long csplit0,
    const unsigned short* __restrict__ A1, const unsigned short* __restrict__ B1,
    void* __restrict__ C1v, int ldc1, long csplit1, int Kfull, int Klen) {
  __shared__ unsigned short Asl[64 * 32];
  __shared__ unsigned short Bsl[128 * 32];

  int yt = blockIdx.y;
  const unsigned short* A;
  const unsigned short* B;
  char* C;
  int ldc;
  long csplit;
  if (yt < n0tiles) { A = A0; B = B0; C = (char*)C0v; ldc = ldc0; csplit = csplit0; }
  else { A = A1; B = B1; C = (char*)C1v; ldc = ldc1; csplit = csplit1; yt -= n0tiles; }
  C += (long)blockIdx.z * csplit;

  const int mt = blockIdx.x;
  const int k0base = blockIdx.z * Klen;
  const unsigned short* Ab = A + (size_t)mt * 64 * Kfull;
  const unsigned short* Bb = B + (size_t)yt * 128 * Kfull;

  const int tid = threadIdx.x;
  const int wave = tid >> 6, lane = tid & 63;
  const int mw = (wave >> 1) * 32, nw = (wave & 1) * 64;
  const int l16 = lane & 15, quad = lane >> 4;

  f32x4 acc[2][4] = {};

  for (int k0 = k0base; k0 < k0base + Klen; k0 += 32) {
    // A: 256 chunks (1/thread), B: 512 chunks (2/thread); 16B per chunk.
    {
      int c = tid;
      int row = c >> 2;
      int ls = (c & 3) ^ ((row >> 1) & 3);
      gld_lds16(Ab + (size_t)row * Kfull + k0 + ls * 8, &Asl[c * 8]);
    }
#pragma unroll
    for (int i = 0; i < 2; ++i) {
      int c = i * 256 + tid;
      int row = c >> 2;
      int ls = (c & 3) ^ ((row >> 1) & 3);
      gld_lds16(Bb + (size_t)row * Kfull + k0 + ls * 8, &Bsl[c * 8]);
    }
    __syncthreads();

    bf16x8 af[2], bfr[4];
#pragma unroll
    for (int t = 0; t < 2; ++t) {
      int row = mw + t * 16 + l16;
      af[t] = *(const bf16x8*)&Asl[row * 32 + ((quad ^ ((row >> 1) & 3)) << 3)];
    }
#pragma unroll
    for (int t = 0; t < 4; ++t) {
      int row = nw + t * 16 + l16;
      bfr[t] = *(const bf16x8*)&Bsl[row * 32 + ((quad ^ ((row >> 1) & 3)) << 3)];
    }
#pragma unroll
    for (int tm = 0; tm < 2; ++tm)
#pragma unroll
      for (int tn = 0; tn < 4; ++tn)
        acc[tm][tn] = __builtin_amdgcn_mfma_f32_16x16x32_bf16(af[tm], bfr[tn], acc[tm][tn], 0, 0, 0);
    __syncthreads();
  }

  // Epilogue: C/D layout col=lane&15, row=quad*4+reg (m89-verified).
  const int mbase = mt * 64 + mw;
  const int nbase = yt * 128 + nw;
#pragma unroll
  for (int tm = 0; tm < 2; ++tm) {
#pragma unroll
    for (int tn = 0; tn < 4; ++tn) {
      int col = nbase + tn * 16 + l16;
      int row0 = mbase + tm * 16 + quad * 4;
#pragma unroll
      for (int r = 0; r < 4; ++r) {
        float v = acc[tm][tn][r];
        if (MODE == 0) {
          v = fmaxf(v, 0.0f);
          ((unsigned short*)C)[(size_t)(row0 + r) * ldc + col] = f2bf(v);
        } else {
          ((float*)C)[(size_t)(row0 + r) * ldc + col] = v;
        }
      }
    }
  }
}

// ---------------------------------------------------------------------------
__device__ __forceinline__ void mm3(const float* a, const float* b, float* c) {
#pragma unroll
  for (int r = 0; r < 3; ++r)
#pragma unroll
    for (int cc = 0; cc < 3; ++cc)
      c[r * 3 + cc] = a[r * 3 + 0] * b[0 + cc] + a[r * 3 + 1] * b[3 + cc] + a[r * 3 + 2] * b[6 + cc];
}

// expm(3x3) + output assembly; sums the two split-K partials.
__global__ void finalize_k(const float* __restrict__ om_p, const float* __restrict__ tr_p,
                           float* __restrict__ out) {
  const int k = blockIdx.x * 256 + threadIdx.x;  // 0..2047
  const int j = blockIdx.y;                      // 0..127

  float a[9];
#pragma unroll
  for (int i = 0; i < 9; ++i)
    a[i] = om_p[(size_t)k * 1152 + 9 * j + i] + om_p[2359296 + (size_t)k * 1152 + 9 * j + i];

  float* omega  = out;
  float* transf = out + (size_t)1152 * 2048;
  float* rot    = out + (size_t)(1152 + 1536) * 2048;
  float* transl = out + (size_t)(1152 + 1536 + 1152) * 2048;

#pragma unroll
  for (int i = 0; i < 9; ++i) omega[(size_t)(9 * j + i) * 2048 + k] = a[i];

  // scaling-and-squaring + order-12 Taylor (scaled ||A||_1 <= 0.25)
  float n1 = 0.f;
#pragma unroll
  for (int c = 0; c < 3; ++c) {
    float s = fabsf(a[c]) + fabsf(a[3 + c]) + fabsf(a[6 + c]);
    n1 = fmaxf(n1, s);
  }
  int s = 0;
  if (n1 > 0.25f) {
    s = (int)ceilf(log2f(n1 * 4.0f));
    if (s < 0) s = 0;
  }
  const float scl = exp2f((float)(-s));
  float As[9];
#pragma unroll
  for (int i = 0; i < 9; ++i) As[i] = a[i] * scl;

  float E[9] = {1, 0, 0, 0, 1, 0, 0, 0, 1};
  float T[9] = {1, 0, 0, 0, 1, 0, 0, 0, 1};
#pragma unroll
  for (int t = 1; t <= 12; ++t) {
    float Tn[9];
    mm3(T, As, Tn);
    const float inv = 1.0f / (float)t;
#pragma unroll
    for (int i = 0; i < 9; ++i) { T[i] = Tn[i] * inv; E[i] += T[i]; }
  }
  for (int q = 0; q < s; ++q) {
    float Tn[9];
    mm3(E, E, Tn);
#pragma unroll
    for (int i = 0; i < 9; ++i) E[i] = Tn[i];
  }

#pragma unroll
  for (int i = 0; i < 9; ++i) {
    rot[(size_t)(9 * j + i) * 2048 + k] = E[i];
    transf[(size_t)(12 * j + i) * 2048 + k] = E[i];
  }
  float tr[3];
#pragma unroll
  for (int c = 0; c < 3; ++c)
    tr[c] = tr_p[(size_t)k * 384 + 3 * j + c] + tr_p[786432 + (size_t)k * 384 + 3 * j + c];
#pragma unroll
  for (int c = 0; c < 3; ++c) {
    transf[(size_t)(12 * j + 9 + c) * 2048 + k] = tr[c];
    transl[(size_t)(3 * j + c) * 2048 + k] = tr[c];
  }
}

// ---------------------------------------------------------------------------
extern "C" void kernel_launch(void* const* d_in, const int* in_sizes, int n_in,
                              void* d_out, int out_size, void* d_ws, size_t ws_size,
                              hipStream_t stream) {
  const float* x   = (const float*)d_in[0];
  const float* Wo0 = (const float*)d_in[1];
  const float* Wo1 = (const float*)d_in[2];
  const float* Wo2 = (const float*)d_in[3];
  const float* Wo3 = (const float*)d_in[4];
  const float* Wt0 = (const float*)d_in[5];
  const float* Wt1 = (const float*)d_in[6];
  const float* Wt2 = (const float*)d_in[7];
  const float* Wt3 = (const float*)d_in[8];

  unsigned short* wb   = (unsigned short*)d_ws;
  unsigned short* wo0b = wb + 0;
  unsigned short* wo1b = wb + 262144;
  unsigned short* wo2b = wb + 4456448;
  unsigned short* wo3b = wb + 8650752;
  unsigned short* wt0b = wb + 11010048;
  unsigned short* wt1b = wb + 11272192;
  unsigned short* wt2b = wb + 15466496;
  unsigned short* wt3b = wb + 19660800;
  unsigned short* Xt   = wb + 20447232;  // 2048 x 128
  unsigned short* HoA  = Xt + 262144;    // 2048 x 2048 bf16 each
  unsigned short* HoB  = HoA + 4194304;
  unsigned short* HtA  = HoB + 4194304;
  unsigned short* HtB  = HtA + 4194304;
  float* om_p = (float*)(HtB + 4194304);   // 2 x (2048 x 1152) fp32 partials
  float* tr_p = om_p + 2 * 2359296;        // 2 x (2048 x 384)  fp32 partials
  // total ws use ~100 MB

  cast_weights_k<<<19968, 256, 0, stream>>>(Wo0, Wo1, Wo2, Wo3, Wt0, Wt1, Wt2, Wt3, wb);
  transpose_cast_k<<<dim3(64, 4), dim3(32, 8), 0, stream>>>(x, Xt);

  // L0: K=128
  gemm_tn<0><<<dim3(32, 32, 1), 256, 0, stream>>>(Xt, wo0b, HoA, 16, 2048, 0,
                                                  Xt, wt0b, HtA, 2048, 0, 128, 128);
  // L1
  gemm_tn<0><<<dim3(32, 32, 1), 256, 0, stream>>>(HoA, wo1b, HoB, 16, 2048, 0,
                                                  HtA, wt1b, HtB, 2048, 0, 2048, 2048);
  // L2
  gemm_tn<0><<<dim3(32, 32, 1), 256, 0, stream>>>(HoB, wo2b, HoA, 16, 2048, 0,
                                                  HtB, wt2b, HtA, 2048, 0, 2048, 2048);
  // L3: omega (N=1152) + translations (N=384), fp32 out, split-K=2
  gemm_tn<1><<<dim3(32, 12, 2), 256, 0, stream>>>(HoA, wo3b, om_p, 9, 1152, (long)2359296 * 4,
                                                  HtA, wt3b, tr_p, 384, (long)786432 * 4, 2048, 1024);

  finalize_k<<<dim3(8, 128), 256, 0, stream>>>(om_p, tr_p, (float*)d_out);
}

// Round 3
// 258.081 us; speedup vs baseline: 1.1748x; 1.1748x over previous
//
#include <hip/hip_runtime.h>
#include <stdint.h>

// LATENT=128, HIDDEN=2048, N_PARTS=128, K=2048
// outputs: omega(1152,2048) transf(1536,2048) rot(1152,2048) transl(384,2048)

typedef short bf16x8 __attribute__((ext_vector_type(8)));
typedef float f32x4 __attribute__((ext_vector_type(4)));

__device__ __forceinline__ unsigned short f2bf(float f) {
  unsigned int x = __float_as_uint(f);
  unsigned int r = (x + 0x7fffu + ((x >> 16) & 1u)) >> 16;
  return (unsigned short)r;
}

__device__ __forceinline__ void gld_lds16(const void* g, void* l) {
  __builtin_amdgcn_global_load_lds(
      (__attribute__((address_space(1))) void*)(g),
      (__attribute__((address_space(3))) void*)(l),
      16, 0, 0);
}

// ---------------------------------------------------------------------------
__global__ void cast_weights_k(const float* __restrict__ wo0, const float* __restrict__ wo1,
                               const float* __restrict__ wo2, const float* __restrict__ wo3,
                               const float* __restrict__ wt0, const float* __restrict__ wt1,
                               const float* __restrict__ wt2, const float* __restrict__ wt3,
                               unsigned short* __restrict__ dst) {
  int gid = blockIdx.x * 256 + threadIdx.x;
  int idx = gid * 4;
  if (idx >= 20447232) return;
  const float* src;
  int off;
  if (idx < 8650752) {
    if (idx < 262144)       { src = wo0; off = idx; }
    else if (idx < 4456448) { src = wo1; off = idx - 262144; }
    else                    { src = wo2; off = idx - 4456448; }
  } else {
    if (idx < 11010048)      { src = wo3; off = idx - 8650752; }
    else if (idx < 11272192) { src = wt0; off = idx - 11010048; }
    else if (idx < 15466496) { src = wt1; off = idx - 11272192; }
    else if (idx < 19660800) { src = wt2; off = idx - 15466496; }
    else                     { src = wt3; off = idx - 19660800; }
  }
  float4 v = *(const float4*)(src + off);
  ushort4 o;
  o.x = f2bf(v.x); o.y = f2bf(v.y); o.z = f2bf(v.z); o.w = f2bf(v.w);
  *(ushort4*)(dst + idx) = o;
}

// ---------------------------------------------------------------------------
// x (128 x 2048) fp32 -> Xt (2048 x 128) bf16
__global__ void transpose_cast_k(const float* __restrict__ x, unsigned short* __restrict__ xt) {
  __shared__ float tile[32][33];
  const int bx = blockIdx.x, by = blockIdx.y;
  const int tx = threadIdx.x, ty = threadIdx.y;
#pragma unroll
  for (int i = 0; i < 32; i += 8)
    tile[ty + i][tx] = x[(size_t)(by * 32 + ty + i) * 2048 + bx * 32 + tx];
  __syncthreads();
#pragma unroll
  for (int i = 0; i < 32; i += 8)
    xt[(size_t)(bx * 32 + ty + i) * 128 + by * 32 + tx] = f2bf(tile[tx][ty + i]);
}

// ---------------------------------------------------------------------------
// TN GEMM: C(M x N) = A(M x K) * B(N x K)^T, bf16 in, fp32 acc.
// Tile TM(64|128) x 128(N), BK=64, 256 threads = 4 waves 2x2, N-wave = 64.
// Two independent problems fused via yt; split-K via blockIdx.z (MODE 1).
// SWZ=1: 1-D grid of 512 decoded so each XCD (blockIdx%8) gets an 8x8
// (mt x yt) sub-grid of ONE chain -> 4 MB unique working set = one L2.
// LDS bank swizzle: physical 16B chunk p at row r holds logical seg p^(r&7);
// rows are 128 B (full bank sweep), so each 16-lane read phase hits every
// bank group exactly twice (free, m136).
// MODE 0: relu + bf16 out.  MODE 1: fp32 out, no relu.
template <int MODE, int TM, int SWZ>
__global__ __launch_bounds__(256, 2) void gemm_tn(
    const unsigned short* __restrict__ A0, const unsigned short* __restrict__ B0,
    void* __restrict__ C0v, int n0tiles, int ldc0, long csplit0,
    const unsigned short* __restrict__ A1, const unsigned short* __restrict__ B1,
    void* __restrict__ C1v, int ldc1, long csplit1, int Kfull, int Klen) {
  __shared__ unsigned short Asl[TM * 64];
  __shared__ unsigned short Bsl[128 * 64];
  constexpr int TMW = TM / 32;  // 16-row m-subtiles per wave

  int mt, yt;
  if (SWZ) {
    int id = blockIdx.x;
    int xcd = id & 7, s = id >> 3;
    mt = ((xcd & 1) << 3) + (s & 7);
    yt = ((xcd >> 1) << 3) + (s >> 3);
  } else {
    mt = blockIdx.x;
    yt = blockIdx.y;
  }

  const unsigned short* A;
  const unsigned short* B;
  char* C;
  int ldc;
  long csplit;
  if (yt < n0tiles) { A = A0; B = B0; C = (char*)C0v; ldc = ldc0; csplit = csplit0; }
  else { A = A1; B = B1; C = (char*)C1v; ldc = ldc1; csplit = csplit1; yt -= n0tiles; }
  C += (long)blockIdx.z * csplit;

  const int k0base = blockIdx.z * Klen;
  const unsigned short* Ab = A + (size_t)mt * TM * Kfull;
  const unsigned short* Bb = B + (size_t)yt * 128 * Kfull;

  const int tid = threadIdx.x;
  const int wave = tid >> 6, lane = tid & 63;
  const int mw = (wave >> 1) * (TM / 2), nw = (wave & 1) * 64;
  const int l16 = lane & 15, quad = lane >> 4;

  f32x4 acc[TMW][4] = {};

  for (int k0 = k0base; k0 < k0base + Klen; k0 += 64) {
    // Stage A (TM x 64) and B (128 x 64) bf16 tiles, 16B chunks, async->LDS.
    // chunk c: row = c>>3, phys pos = c&7 holds logical seg (c&7)^(row&7).
#pragma unroll
    for (int i = 0; i < TM / 32; ++i) {
      int c = i * 256 + tid;
      int row = c >> 3;
      int sseg = (c & 7) ^ (row & 7);
      gld_lds16(Ab + (size_t)row * Kfull + k0 + sseg * 8, &Asl[c * 8]);
    }
#pragma unroll
    for (int i = 0; i < 4; ++i) {
      int c = i * 256 + tid;
      int row = c >> 3;
      int sseg = (c & 7) ^ (row & 7);
      gld_lds16(Bb + (size_t)row * Kfull + k0 + sseg * 8, &Bsl[c * 8]);
    }
    __syncthreads();

#pragma unroll
    for (int h = 0; h < 2; ++h) {  // two k=32 sub-steps of the BK=64 tile
      bf16x8 af[TMW], bfr[4];
#pragma unroll
      for (int t = 0; t < TMW; ++t) {
        int row = mw + t * 16 + l16;
        int p = (h * 4 + quad) ^ (row & 7);
        af[t] = *(const bf16x8*)&Asl[row * 64 + p * 8];
      }
#pragma unroll
      for (int t = 0; t < 4; ++t) {
        int row = nw + t * 16 + l16;
        int p = (h * 4 + quad) ^ (row & 7);
        bfr[t] = *(const bf16x8*)&Bsl[row * 64 + p * 8];
      }
#pragma unroll
      for (int tm = 0; tm < TMW; ++tm)
#pragma unroll
        for (int tn = 0; tn < 4; ++tn)
          acc[tm][tn] = __builtin_amdgcn_mfma_f32_16x16x32_bf16(af[tm], bfr[tn], acc[tm][tn], 0, 0, 0);
    }
    __syncthreads();
  }

  // Epilogue: C/D layout col=lane&15, row=quad*4+reg (m89-verified).
  const int mbase = mt * TM + mw;
  const int nbase = yt * 128 + nw;
#pragma unroll
  for (int tm = 0; tm < TMW; ++tm) {
#pragma unroll
    for (int tn = 0; tn < 4; ++tn) {
      int col = nbase + tn * 16 + l16;
      int row0 = mbase + tm * 16 + quad * 4;
#pragma unroll
      for (int r = 0; r < 4; ++r) {
        float v = acc[tm][tn][r];
        if (MODE == 0) {
          v = fmaxf(v, 0.0f);
          ((unsigned short*)C)[(size_t)(row0 + r) * ldc + col] = f2bf(v);
        } else {
          ((float*)C)[(size_t)(row0 + r) * ldc + col] = v;
        }
      }
    }
  }
}

// ---------------------------------------------------------------------------
__device__ __forceinline__ void mm3(const float* a, const float* b, float* c) {
#pragma unroll
  for (int r = 0; r < 3; ++r)
#pragma unroll
    for (int cc = 0; cc < 3; ++cc)
      c[r * 3 + cc] = a[r * 3 + 0] * b[0 + cc] + a[r * 3 + 1] * b[3 + cc] + a[r * 3 + 2] * b[6 + cc];
}

// expm(3x3) + output assembly; sums the two split-K partials.
__global__ void finalize_k(const float* __restrict__ om_p, const float* __restrict__ tr_p,
                           float* __restrict__ out) {
  const int k = blockIdx.x * 256 + threadIdx.x;  // 0..2047
  const int j = blockIdx.y;                      // 0..127

  float a[9];
#pragma unroll
  for (int i = 0; i < 9; ++i)
    a[i] = om_p[(size_t)k * 1152 + 9 * j + i] + om_p[2359296 + (size_t)k * 1152 + 9 * j + i];

  float* omega  = out;
  float* transf = out + (size_t)1152 * 2048;
  float* rot    = out + (size_t)(1152 + 1536) * 2048;
  float* transl = out + (size_t)(1152 + 1536 + 1152) * 2048;

#pragma unroll
  for (int i = 0; i < 9; ++i) omega[(size_t)(9 * j + i) * 2048 + k] = a[i];

  // scaling-and-squaring + order-12 Taylor (scaled ||A||_1 <= 0.25)
  float n1 = 0.f;
#pragma unroll
  for (int c = 0; c < 3; ++c) {
    float s = fabsf(a[c]) + fabsf(a[3 + c]) + fabsf(a[6 + c]);
    n1 = fmaxf(n1, s);
  }
  int s = 0;
  if (n1 > 0.25f) {
    s = (int)ceilf(log2f(n1 * 4.0f));
    if (s < 0) s = 0;
  }
  const float scl = exp2f((float)(-s));
  float As[9];
#pragma unroll
  for (int i = 0; i < 9; ++i) As[i] = a[i] * scl;

  float E[9] = {1, 0, 0, 0, 1, 0, 0, 0, 1};
  float T[9] = {1, 0, 0, 0, 1, 0, 0, 0, 1};
#pragma unroll
  for (int t = 1; t <= 12; ++t) {
    float Tn[9];
    mm3(T, As, Tn);
    const float inv = 1.0f / (float)t;
#pragma unroll
    for (int i = 0; i < 9; ++i) { T[i] = Tn[i] * inv; E[i] += T[i]; }
  }
  for (int q = 0; q < s; ++q) {
    float Tn[9];
    mm3(E, E, Tn);
#pragma unroll
    for (int i = 0; i < 9; ++i) E[i] = Tn[i];
  }

#pragma unroll
  for (int i = 0; i < 9; ++i) {
    rot[(size_t)(9 * j + i) * 2048 + k] = E[i];
    transf[(size_t)(12 * j + i) * 2048 + k] = E[i];
  }
  float tr[3];
#pragma unroll
  for (int c = 0; c < 3; ++c)
    tr[c] = tr_p[(size_t)k * 384 + 3 * j + c] + tr_p[786432 + (size_t)k * 384 + 3 * j + c];
#pragma unroll
  for (int c = 0; c < 3; ++c) {
    transf[(size_t)(12 * j + 9 + c) * 2048 + k] = tr[c];
    transl[(size_t)(3 * j + c) * 2048 + k] = tr[c];
  }
}

// ---------------------------------------------------------------------------
extern "C" void kernel_launch(void* const* d_in, const int* in_sizes, int n_in,
                              void* d_out, int out_size, void* d_ws, size_t ws_size,
                              hipStream_t stream) {
  const float* x   = (const float*)d_in[0];
  const float* Wo0 = (const float*)d_in[1];
  const float* Wo1 = (const float*)d_in[2];
  const float* Wo2 = (const float*)d_in[3];
  const float* Wo3 = (const float*)d_in[4];
  const float* Wt0 = (const float*)d_in[5];
  const float* Wt1 = (const float*)d_in[6];
  const float* Wt2 = (const float*)d_in[7];
  const float* Wt3 = (const float*)d_in[8];

  unsigned short* wb   = (unsigned short*)d_ws;
  unsigned short* wo0b = wb + 0;
  unsigned short* wo1b = wb + 262144;
  unsigned short* wo2b = wb + 4456448;
  unsigned short* wo3b = wb + 8650752;
  unsigned short* wt0b = wb + 11010048;
  unsigned short* wt1b = wb + 11272192;
  unsigned short* wt2b = wb + 15466496;
  unsigned short* wt3b = wb + 19660800;
  unsigned short* Xt   = wb + 20447232;  // 2048 x 128
  unsigned short* HoA  = Xt + 262144;    // 2048 x 2048 bf16 each
  unsigned short* HoB  = HoA + 4194304;
  unsigned short* HtA  = HoB + 4194304;
  unsigned short* HtB  = HtA + 4194304;
  float* om_p = (float*)(HtB + 4194304);   // 2 x (2048 x 1152) fp32 partials
  float* tr_p = om_p + 2 * 2359296;        // 2 x (2048 x 384)  fp32 partials

  cast_weights_k<<<19968, 256, 0, stream>>>(Wo0, Wo1, Wo2, Wo3, Wt0, Wt1, Wt2, Wt3, wb);
  transpose_cast_k<<<dim3(64, 4), dim3(32, 8), 0, stream>>>(x, Xt);

  // L0: K=128
  gemm_tn<0, 128, 1><<<512, 256, 0, stream>>>(Xt, wo0b, HoA, 16, 2048, 0,
                                              Xt, wt0b, HtA, 2048, 0, 128, 128);
  // L1
  gemm_tn<0, 128, 1><<<512, 256, 0, stream>>>(HoA, wo1b, HoB, 16, 2048, 0,
                                              HtA, wt1b, HtB, 2048, 0, 2048, 2048);
  // L2
  gemm_tn<0, 128, 1><<<512, 256, 0, stream>>>(HoB, wo2b, HoA, 16, 2048, 0,
                                              HtB, wt2b, HtA, 2048, 0, 2048, 2048);
  // L3: omega (N=1152) + translations (N=384), fp32 out, split-K=2, TM=64
  gemm_tn<1, 64, 0><<<dim3(32, 12, 2), 256, 0, stream>>>(
      HoA, wo3b, om_p, 9, 1152, (long)2359296 * 4,
      HtA, wt3b, tr_p, 384, (long)786432 * 4, 2048, 1024);

  finalize_k<<<dim3(8, 128), 256, 0, stream>>>(om_p, tr_p, (float*)d_out);
}

// Round 5
// 246.060 us; speedup vs baseline: 1.2322x; 1.0489x over previous
//
#include <hip/hip_runtime.h>
#include <stdint.h>

// LATENT=128, HIDDEN=2048, N_PARTS=128, K=2048
// outputs: omega(1152,2048) transf(1536,2048) rot(1152,2048) transl(384,2048)

typedef short bf16x8 __attribute__((ext_vector_type(8)));
typedef float f32x4 __attribute__((ext_vector_type(4)));

__device__ __forceinline__ unsigned short f2bf(float f) {
  unsigned int x = __float_as_uint(f);
  unsigned int r = (x + 0x7fffu + ((x >> 16) & 1u)) >> 16;
  return (unsigned short)r;
}

__device__ __forceinline__ void gld_lds16(const void* g, void* l) {
  __builtin_amdgcn_global_load_lds(
      (__attribute__((address_space(1))) void*)(g),
      (__attribute__((address_space(3))) void*)(l),
      16, 0, 0);
}

// ---------------------------------------------------------------------------
// Weight fp32 -> bf16 cast; 8 floats/thread, 16 B stores. 20447232 elems.
__global__ void cast_weights_k(const float* __restrict__ wo0, const float* __restrict__ wo1,
                               const float* __restrict__ wo2, const float* __restrict__ wo3,
                               const float* __restrict__ wt0, const float* __restrict__ wt1,
                               const float* __restrict__ wt2, const float* __restrict__ wt3,
                               unsigned short* __restrict__ dst) {
  int gid = blockIdx.x * 256 + threadIdx.x;
  int idx = gid * 8;
  if (idx >= 20447232) return;
  const float* src;
  int off;
  if (idx < 8650752) {
    if (idx < 262144)       { src = wo0; off = idx; }
    else if (idx < 4456448) { src = wo1; off = idx - 262144; }
    else                    { src = wo2; off = idx - 4456448; }
  } else {
    if (idx < 11010048)      { src = wo3; off = idx - 8650752; }
    else if (idx < 11272192) { src = wt0; off = idx - 11010048; }
    else if (idx < 15466496) { src = wt1; off = idx - 11272192; }
    else if (idx < 19660800) { src = wt2; off = idx - 15466496; }
    else                     { src = wt3; off = idx - 19660800; }
  }
  float4 a = *(const float4*)(src + off);
  float4 b = *(const float4*)(src + off + 4);
  uint4 o;
  o.x = (unsigned)f2bf(a.x) | ((unsigned)f2bf(a.y) << 16);
  o.y = (unsigned)f2bf(a.z) | ((unsigned)f2bf(a.w) << 16);
  o.z = (unsigned)f2bf(b.x) | ((unsigned)f2bf(b.y) << 16);
  o.w = (unsigned)f2bf(b.z) | ((unsigned)f2bf(b.w) << 16);
  *(uint4*)(dst + idx) = o;
}

// ---------------------------------------------------------------------------
// x (128 x 2048) fp32 -> Xt (2048 x 128) bf16
__global__ void transpose_cast_k(const float* __restrict__ x, unsigned short* __restrict__ xt) {
  __shared__ float tile[32][33];
  const int bx = blockIdx.x, by = blockIdx.y;
  const int tx = threadIdx.x, ty = threadIdx.y;
#pragma unroll
  for (int i = 0; i < 32; i += 8)
    tile[ty + i][tx] = x[(size_t)(by * 32 + ty + i) * 2048 + bx * 32 + tx];
  __syncthreads();
#pragma unroll
  for (int i = 0; i < 32; i += 8)
    xt[(size_t)(bx * 32 + ty + i) * 128 + by * 32 + tx] = f2bf(tile[tx][ty + i]);
}

// ---------------------------------------------------------------------------
// TN GEMM: C(M x N) = A(M x K) * B(N x K)^T, bf16 in, fp32 acc.
// Tile TM(64|128) x 128(N), BK=128, 256 threads = 4 waves 2x2, N-wave = 64.
// BK=128 (64 KB LDS at TM=128, still 2 blocks/CU) halves the number of
// barrier+vmcnt drains — the measured ~40% non-pipe residual of round 3.
// Two independent problems fused via yt; split-K via blockIdx.z (MODE 1).
// SWZ=1: each XCD (blockIdx%8) gets an 8x8 (mt x yt) sub-grid of one chain
// -> 4 MB working set = one L2 (FETCH halved, measured round 3).
// LDS bank swizzle: rows are 256 B = 16 chunks of 16 B; physical chunk p of
// row r holds logical chunk p^(r&15). Read phases hit each bank-group 2x
// (free, m136); staging stays lane-contiguous (global_load_lds-legal).
// MODE 0: relu + bf16 out (row-major).  MODE 1: fp32 out, n-major, float4.
template <int MODE, int TM, int SWZ>
__global__ __launch_bounds__(256, 2) void gemm_tn(
    const unsigned short* __restrict__ A0, const unsigned short* __restrict__ B0,
    void* __restrict__ C0v, int n0tiles, int ldc0, long csplit0,
    const unsigned short* __restrict__ A1, const unsigned short* __restrict__ B1,
    void* __restrict__ C1v, int ldc1, long csplit1, int Kfull, int Klen) {
  __shared__ alignas(16) unsigned short Asl[TM * 128];
  __shared__ alignas(16) unsigned short Bsl[128 * 128];
  constexpr int TMW = TM / 32;  // 16-row m-subtiles per wave

  int mt, yt;
  if (SWZ) {
    int id = blockIdx.x;
    int xcd = id & 7, s = id >> 3;
    mt = ((xcd & 1) << 3) + (s & 7);
    yt = ((xcd >> 1) << 3) + (s >> 3);
  } else {
    mt = blockIdx.x;
    yt = blockIdx.y;
  }

  const unsigned short* A;
  const unsigned short* B;
  char* C;
  int ldc;
  long csplit;
  if (yt < n0tiles) { A = A0; B = B0; C = (char*)C0v; ldc = ldc0; csplit = csplit0; }
  else { A = A1; B = B1; C = (char*)C1v; ldc = ldc1; csplit = csplit1; yt -= n0tiles; }
  C += (long)blockIdx.z * csplit;

  const int k0base = blockIdx.z * Klen;
  const unsigned short* Ab = A + (size_t)mt * TM * Kfull;
  const unsigned short* Bb = B + (size_t)yt * 128 * Kfull;

  const int tid = threadIdx.x;
  const int wave = tid >> 6, lane = tid & 63;
  const int mw = (wave >> 1) * (TM / 2), nw = (wave & 1) * 64;
  const int l16 = lane & 15, quad = lane >> 4;

  f32x4 acc[TMW][4] = {};

  for (int k0 = k0base; k0 < k0base + Klen; k0 += 128) {
    // Stage A (TM x 128) and B (128 x 128) bf16 tiles; 16 chunks of 16 B per
    // row; phys chunk c&15 holds logical chunk (c&15)^(row&15).
#pragma unroll
    for (int i = 0; i < TM / 16; ++i) {
      int c = i * 256 + tid;
      int row = c >> 4;
      int l = (c & 15) ^ (row & 15);
      gld_lds16(Ab + (size_t)row * Kfull + k0 + l * 8, &Asl[c * 8]);
    }
#pragma unroll
    for (int i = 0; i < 8; ++i) {
      int c = i * 256 + tid;
      int row = c >> 4;
      int l = (c & 15) ^ (row & 15);
      gld_lds16(Bb + (size_t)row * Kfull + k0 + l * 8, &Bsl[c * 8]);
    }
    __syncthreads();

#pragma unroll
    for (int h = 0; h < 4; ++h) {  // four k=32 sub-steps of the BK=128 tile
      bf16x8 af[TMW], bfr[4];
#pragma unroll
      for (int t = 0; t < TMW; ++t) {
        int row = mw + t * 16 + l16;
        int p = (h * 4 + quad) ^ (row & 15);
        af[t] = *(const bf16x8*)&Asl[row * 128 + p * 8];
      }
#pragma unroll
      for (int t = 0; t < 4; ++t) {
        int row = nw + t * 16 + l16;
        int p = (h * 4 + quad) ^ (row & 15);
        bfr[t] = *(const bf16x8*)&Bsl[row * 128 + p * 8];
      }
#pragma unroll
      for (int tm = 0; tm < TMW; ++tm)
#pragma unroll
        for (int tn = 0; tn < 4; ++tn)
          acc[tm][tn] = __builtin_amdgcn_mfma_f32_16x16x32_bf16(af[tm], bfr[tn], acc[tm][tn], 0, 0, 0);
    }
    __syncthreads();
  }

  // Epilogue: C/D layout col=lane&15, row=quad*4+reg (m89-verified).
  const int mbase = mt * TM + mw;
  const int nbase = yt * 128 + nw;
#pragma unroll
  for (int tm = 0; tm < TMW; ++tm) {
#pragma unroll
    for (int tn = 0; tn < 4; ++tn) {
      int col = nbase + tn * 16 + l16;
      int row0 = mbase + tm * 16 + quad * 4;
      if (MODE == 0) {
#pragma unroll
        for (int r = 0; r < 4; ++r) {
          float v = fmaxf(acc[tm][tn][r], 0.0f);
          ((unsigned short*)C)[(size_t)(row0 + r) * ldc + col] = f2bf(v);
        }
      } else {
        // n-major fp32: C[col * ldc + row], 4 consecutive rows -> one float4
        *(f32x4*)((float*)C + (size_t)col * ldc + row0) = acc[tm][tn];
      }
    }
  }
}

// ---------------------------------------------------------------------------
__device__ __forceinline__ void mm3(const float* a, const float* b, float* c) {
#pragma unroll
  for (int r = 0; r < 3; ++r)
#pragma unroll
    for (int cc = 0; cc < 3; ++cc)
      c[r * 3 + cc] = a[r * 3 + 0] * b[0 + cc] + a[r * 3 + 1] * b[3 + cc] + a[r * 3 + 2] * b[6 + cc];
}

// expm(3x3) + output assembly; partials are n-major -> fully coalesced reads.
__global__ void finalize_k(const float* __restrict__ om_p, const float* __restrict__ tr_p,
                           float* __restrict__ out) {
  const int k = blockIdx.x * 256 + threadIdx.x;  // 0..2047
  const int j = blockIdx.y;                      // 0..127

  float a[9];
#pragma unroll
  for (int i = 0; i < 9; ++i)
    a[i] = om_p[(size_t)(9 * j + i) * 2048 + k] + om_p[2359296 + (size_t)(9 * j + i) * 2048 + k];

  float* omega  = out;
  float* transf = out + (size_t)1152 * 2048;
  float* rot    = out + (size_t)(1152 + 1536) * 2048;
  float* transl = out + (size_t)(1152 + 1536 + 1152) * 2048;

#pragma unroll
  for (int i = 0; i < 9; ++i) omega[(size_t)(9 * j + i) * 2048 + k] = a[i];

  // scaling-and-squaring + order-12 Taylor (scaled ||A||_1 <= 0.25)
  float n1 = 0.f;
#pragma unroll
  for (int c = 0; c < 3; ++c) {
    float s = fabsf(a[c]) + fabsf(a[3 + c]) + fabsf(a[6 + c]);
    n1 = fmaxf(n1, s);
  }
  int s = 0;
  if (n1 > 0.25f) {
    s = (int)ceilf(log2f(n1 * 4.0f));
    if (s < 0) s = 0;
  }
  const float scl = exp2f((float)(-s));
  float As[9];
#pragma unroll
  for (int i = 0; i < 9; ++i) As[i] = a[i] * scl;

  float E[9] = {1, 0, 0, 0, 1, 0, 0, 0, 1};
  float T[9] = {1, 0, 0, 0, 1, 0, 0, 0, 1};
#pragma unroll
  for (int t = 1; t <= 12; ++t) {
    float Tn[9];
    mm3(T, As, Tn);
    const float inv = 1.0f / (float)t;
#pragma unroll
    for (int i = 0; i < 9; ++i) { T[i] = Tn[i] * inv; E[i] += T[i]; }
  }
  for (int q = 0; q < s; ++q) {
    float Tn[9];
    mm3(E, E, Tn);
#pragma unroll
    for (int i = 0; i < 9; ++i) E[i] = Tn[i];
  }

#pragma unroll
  for (int i = 0; i < 9; ++i) {
    rot[(size_t)(9 * j + i) * 2048 + k] = E[i];
    transf[(size_t)(12 * j + i) * 2048 + k] = E[i];
  }
  float tr[3];
#pragma unroll
  for (int c = 0; c < 3; ++c)
    tr[c] = tr_p[(size_t)(3 * j + c) * 2048 + k] + tr_p[786432 + (size_t)(3 * j + c) * 2048 + k];
#pragma unroll
  for (int c = 0; c < 3; ++c) {
    transf[(size_t)(12 * j + 9 + c) * 2048 + k] = tr[c];
    transl[(size_t)(3 * j + c) * 2048 + k] = tr[c];
  }
}

// ---------------------------------------------------------------------------
extern "C" void kernel_launch(void* const* d_in, const int* in_sizes, int n_in,
                              void* d_out, int out_size, void* d_ws, size_t ws_size,
                              hipStream_t stream) {
  const float* x   = (const float*)d_in[0];
  const float* Wo0 = (const float*)d_in[1];
  const float* Wo1 = (const float*)d_in[2];
  const float* Wo2 = (const float*)d_in[3];
  const float* Wo3 = (const float*)d_in[4];
  const float* Wt0 = (const float*)d_in[5];
  const float* Wt1 = (const float*)d_in[6];
  const float* Wt2 = (const float*)d_in[7];
  const float* Wt3 = (const float*)d_in[8];

  unsigned short* wb   = (unsigned short*)d_ws;
  unsigned short* wo0b = wb + 0;
  unsigned short* wo1b = wb + 262144;
  unsigned short* wo2b = wb + 4456448;
  unsigned short* wo3b = wb + 8650752;
  unsigned short* wt0b = wb + 11010048;
  unsigned short* wt1b = wb + 11272192;
  unsigned short* wt2b = wb + 15466496;
  unsigned short* wt3b = wb + 19660800;
  unsigned short* Xt   = wb + 20447232;  // 2048 x 128
  unsigned short* HoA  = Xt + 262144;    // 2048 x 2048 bf16 each
  unsigned short* HoB  = HoA + 4194304;
  unsigned short* HtA  = HoB + 4194304;
  unsigned short* HtB  = HtA + 4194304;
  float* om_p = (float*)(HtB + 4194304);   // 2 x (1152 x 2048) fp32, n-major
  float* tr_p = om_p + 2 * 2359296;        // 2 x (384 x 2048)  fp32, n-major

  cast_weights_k<<<9984, 256, 0, stream>>>(Wo0, Wo1, Wo2, Wo3, Wt0, Wt1, Wt2, Wt3, wb);
  transpose_cast_k<<<dim3(64, 4), dim3(32, 8), 0, stream>>>(x, Xt);

  // L0: K=128 -> single K-iteration
  gemm_tn<0, 128, 1><<<512, 256, 0, stream>>>(Xt, wo0b, HoA, 16, 2048, 0,
                                              Xt, wt0b, HtA, 2048, 0, 128, 128);
  // L1
  gemm_tn<0, 128, 1><<<512, 256, 0, stream>>>(HoA, wo1b, HoB, 16, 2048, 0,
                                              HtA, wt1b, HtB, 2048, 0, 2048, 2048);
  // L2
  gemm_tn<0, 128, 1><<<512, 256, 0, stream>>>(HoB, wo2b, HoA, 16, 2048, 0,
                                              HtB, wt2b, HtA, 2048, 0, 2048, 2048);
  // L3: omega (N=1152, 9 tiles) + translations (N=384, 3 tiles), fp32 n-major
  // (ldc = M = 2048 for both), split-K=2, TM=64
  gemm_tn<1, 64, 0><<<dim3(32, 12, 2), 256, 0, stream>>>(
      HoA, wo3b, om_p, 9, 2048, (long)2359296 * 4,
      HtA, wt3b, tr_p, 2048, (long)786432 * 4, 2048, 1024);

  finalize_k<<<dim3(8, 128), 256, 0, stream>>>(om_p, tr_p, (float*)d_out);
}

// Round 6
// 240.540 us; speedup vs baseline: 1.2605x; 1.0229x over previous
//
#include <hip/hip_runtime.h>
#include <stdint.h>

// LATENT=128, HIDDEN=2048, N_PARTS=128, K=2048
// outputs: omega(1152,2048) transf(1536,2048) rot(1152,2048) transl(384,2048)

typedef short bf16x8 __attribute__((ext_vector_type(8)));
typedef float f32x4 __attribute__((ext_vector_type(4)));

__device__ __forceinline__ unsigned short f2bf(float f) {
  unsigned int x = __float_as_uint(f);
  unsigned int r = (x + 0x7fffu + ((x >> 16) & 1u)) >> 16;
  return (unsigned short)r;
}

__device__ __forceinline__ void gld_lds16(const void* g, void* l) {
  __builtin_amdgcn_global_load_lds(
      (__attribute__((address_space(1))) void*)(g),
      (__attribute__((address_space(3))) void*)(l),
      16, 0, 0);
}

// ---------------------------------------------------------------------------
// Prep: blocks 0..9983 cast all 8 weights fp32->bf16 (8 elems/thread, 16 B
// stores); blocks 9984..10239 transpose+cast x (128x2048) -> Xt (2048x128).
__global__ void prep_k(const float* __restrict__ x,
                       const float* __restrict__ wo0, const float* __restrict__ wo1,
                       const float* __restrict__ wo2, const float* __restrict__ wo3,
                       const float* __restrict__ wt0, const float* __restrict__ wt1,
                       const float* __restrict__ wt2, const float* __restrict__ wt3,
                       unsigned short* __restrict__ dst, unsigned short* __restrict__ xt) {
  __shared__ float tile[32][33];
  const int b = blockIdx.x;
  const int tid = threadIdx.x;
  if (b >= 9984) {
    const int r = b - 9984;
    const int bx = r & 63, by = r >> 6;
    const int tx = tid & 31, ty = tid >> 5;
#pragma unroll
    for (int i = 0; i < 32; i += 8)
      tile[ty + i][tx] = x[(size_t)(by * 32 + ty + i) * 2048 + bx * 32 + tx];
    __syncthreads();
#pragma unroll
    for (int i = 0; i < 32; i += 8)
      xt[(size_t)(bx * 32 + ty + i) * 128 + by * 32 + tx] = f2bf(tile[tx][ty + i]);
    return;
  }
  int idx = (b * 256 + tid) * 8;
  if (idx >= 20447232) return;
  const float* src;
  int off;
  if (idx < 8650752) {
    if (idx < 262144)       { src = wo0; off = idx; }
    else if (idx < 4456448) { src = wo1; off = idx - 262144; }
    else                    { src = wo2; off = idx - 4456448; }
  } else {
    if (idx < 11010048)      { src = wo3; off = idx - 8650752; }
    else if (idx < 11272192) { src = wt0; off = idx - 11010048; }
    else if (idx < 15466496) { src = wt1; off = idx - 11272192; }
    else if (idx < 19660800) { src = wt2; off = idx - 15466496; }
    else                     { src = wt3; off = idx - 19660800; }
  }
  float4 a = *(const float4*)(src + off);
  float4 c = *(const float4*)(src + off + 4);
  uint4 o;
  o.x = (unsigned)f2bf(a.x) | ((unsigned)f2bf(a.y) << 16);
  o.y = (unsigned)f2bf(a.z) | ((unsigned)f2bf(a.w) << 16);
  o.z = (unsigned)f2bf(c.x) | ((unsigned)f2bf(c.y) << 16);
  o.w = (unsigned)f2bf(c.z) | ((unsigned)f2bf(c.w) << 16);
  *(uint4*)(dst + idx) = o;
}

// ---------------------------------------------------------------------------
// Hidden-layer TN GEMM (plateau kernel, unchanged structure from round 5):
// C = A(M x K) * B(N x K)^T, 128x128 tile, BK=128 (64 KB LDS, 2 blocks/CU),
// relu + bf16 row-major out. Two chains fused via yt; XCD swizzle (SWZ).
template <int SWZ>
__global__ __launch_bounds__(256, 2) void gemm_tn(
    const unsigned short* __restrict__ A0, const unsigned short* __restrict__ B0,
    unsigned short* __restrict__ C0, int n0tiles, int ldc0,
    const unsigned short* __restrict__ A1, const unsigned short* __restrict__ B1,
    unsigned short* __restrict__ C1, int ldc1, int K) {
  __shared__ alignas(16) unsigned short Asl[128 * 128];
  __shared__ alignas(16) unsigned short Bsl[128 * 128];

  int mt, yt;
  if (SWZ) {
    int id = blockIdx.x;
    int xcd = id & 7, s = id >> 3;
    mt = ((xcd & 1) << 3) + (s & 7);
    yt = ((xcd >> 1) << 3) + (s >> 3);
  } else {
    mt = blockIdx.x;
    yt = blockIdx.y;
  }

  const unsigned short* A;
  const unsigned short* B;
  unsigned short* C;
  int ldc;
  if (yt < n0tiles) { A = A0; B = B0; C = C0; ldc = ldc0; }
  else { A = A1; B = B1; C = C1; ldc = ldc1; yt -= n0tiles; }

  const unsigned short* Ab = A + (size_t)mt * 128 * K;
  const unsigned short* Bb = B + (size_t)yt * 128 * K;

  const int tid = threadIdx.x;
  const int wave = tid >> 6, lane = tid & 63;
  const int mw = (wave >> 1) * 64, nw = (wave & 1) * 64;
  const int l16 = lane & 15, quad = lane >> 4;

  f32x4 acc[4][4] = {};

  for (int k0 = 0; k0 < K; k0 += 128) {
#pragma unroll
    for (int i = 0; i < 8; ++i) {
      int c = i * 256 + tid;
      int row = c >> 4;
      int l = (c & 15) ^ (row & 15);
      gld_lds16(Ab + (size_t)row * K + k0 + l * 8, &Asl[c * 8]);
      gld_lds16(Bb + (size_t)row * K + k0 + l * 8, &Bsl[c * 8]);
    }
    __syncthreads();

#pragma unroll
    for (int h = 0; h < 4; ++h) {
      bf16x8 af[4], bfr[4];
#pragma unroll
      for (int t = 0; t < 4; ++t) {
        int row = mw + t * 16 + l16;
        int p = (h * 4 + quad) ^ (row & 15);
        af[t] = *(const bf16x8*)&Asl[row * 128 + p * 8];
      }
#pragma unroll
      for (int t = 0; t < 4; ++t) {
        int row = nw + t * 16 + l16;
        int p = (h * 4 + quad) ^ (row & 15);
        bfr[t] = *(const bf16x8*)&Bsl[row * 128 + p * 8];
      }
#pragma unroll
      for (int tm = 0; tm < 4; ++tm)
#pragma unroll
        for (int tn = 0; tn < 4; ++tn)
          acc[tm][tn] = __builtin_amdgcn_mfma_f32_16x16x32_bf16(af[tm], bfr[tn], acc[tm][tn], 0, 0, 0);
    }
    __syncthreads();
  }

  const int mbase = mt * 128 + mw;
  const int nbase = yt * 128 + nw;
#pragma unroll
  for (int tm = 0; tm < 4; ++tm) {
#pragma unroll
    for (int tn = 0; tn < 4; ++tn) {
      int col = nbase + tn * 16 + l16;
      int row0 = mbase + tm * 16 + quad * 4;
#pragma unroll
      for (int r = 0; r < 4; ++r) {
        float v = fmaxf(acc[tm][tn][r], 0.0f);
        C[(size_t)(row0 + r) * ldc + col] = f2bf(v);
      }
    }
  }
}

// ---------------------------------------------------------------------------
__device__ __forceinline__ void mm3(const float* a, const float* b, float* c) {
#pragma unroll
  for (int r = 0; r < 3; ++r)
#pragma unroll
    for (int cc = 0; cc < 3; ++cc)
      c[r * 3 + cc] = a[r * 3 + 0] * b[0 + cc] + a[r * 3 + 1] * b[3 + cc] + a[r * 3 + 2] * b[6 + cc];
}

__device__ __forceinline__ void expm3(const float* a, float* E) {
  // scaling-and-squaring + order-12 Taylor (scaled ||A||_1 <= 0.25)
  float n1 = 0.f;
#pragma unroll
  for (int c = 0; c < 3; ++c) {
    float s = fabsf(a[c]) + fabsf(a[3 + c]) + fabsf(a[6 + c]);
    n1 = fmaxf(n1, s);
  }
  int s = 0;
  if (n1 > 0.25f) {
    s = (int)ceilf(log2f(n1 * 4.0f));
    if (s < 0) s = 0;
  }
  const float scl = exp2f((float)(-s));
  float As[9];
#pragma unroll
  for (int i = 0; i < 9; ++i) As[i] = a[i] * scl;
  float T[9] = {1, 0, 0, 0, 1, 0, 0, 0, 1};
#pragma unroll
  for (int i = 0; i < 9; ++i) E[i] = T[i];
#pragma unroll
  for (int t = 1; t <= 12; ++t) {
    float Tn[9];
    mm3(T, As, Tn);
    const float inv = 1.0f / (float)t;
#pragma unroll
    for (int i = 0; i < 9; ++i) { T[i] = Tn[i] * inv; E[i] += T[i]; }
  }
  for (int q = 0; q < s; ++q) {
    float Tn[9];
    mm3(E, E, Tn);
#pragma unroll
    for (int i = 0; i < 9; ++i) E[i] = Tn[i];
  }
}

// ---------------------------------------------------------------------------
// Final layer + expm + output assembly, single kernel, no partials.
// yt<8 : omega blocks, tile 64(M) x 144(N = 16 parts x 9), A=Ho, B=Wo3.
//        4 waves in 4x1 (wave = 16 m-rows x all 144 n). After K-loop the
//        fp32 C-tile goes through LDS (stride 68 pad -> 2-way bank = free)
//        so each thread owns full 3x3 mats; expm in-register; writes
//        omega + rot + transf[0:9) rows directly (lane = k, coalesced).
// yt>=8: translation blocks, tile 64 x 128, A=Ht, B=Wt3; writes transl and
//        transf[9:12) rows as n-major float4 straight from the accumulator.
__global__ __launch_bounds__(256, 2) void gemm_l3(
    const unsigned short* __restrict__ Ho, const unsigned short* __restrict__ W9,
    const unsigned short* __restrict__ Ht, const unsigned short* __restrict__ W3,
    float* __restrict__ out) {
  __shared__ alignas(16) char smem[16384 + 39168];  // A 16 KB; B(36.9KB)/C(39.2KB) union
  unsigned short* Asl = (unsigned short*)smem;
  unsigned short* Bsl = (unsigned short*)(smem + 16384);
  float* Cl = (float*)(smem + 16384);

  const int mt = blockIdx.x;  // 32 tiles of 64 samples
  const int yt = blockIdx.y;  // 0..7 omega, 8..10 transl
  const int tid = threadIdx.x;
  const int wave = tid >> 6, lane = tid & 63;
  const int l16 = lane & 15, quad = lane >> 4;
  const int mbase = mt * 64;

  float* omega  = out;
  float* transf = out + (size_t)1152 * 2048;
  float* rot    = out + (size_t)(1152 + 1536) * 2048;
  float* transl = out + (size_t)(1152 + 1536 + 1152) * 2048;

  if (yt < 8) {
    const unsigned short* Ab = Ho + (size_t)mbase * 2048;
    const unsigned short* Bb = W9 + (size_t)yt * 144 * 2048;
    const int mw = wave * 16;
    f32x4 acc[9] = {};

    for (int k0 = 0; k0 < 2048; k0 += 128) {
#pragma unroll
      for (int i = 0; i < 4; ++i) {  // A: 64 rows x 16 chunks
        int c = i * 256 + tid;
        int row = c >> 4;
        int l = (c & 15) ^ (row & 15);
        gld_lds16(Ab + (size_t)row * 2048 + k0 + l * 8, &Asl[c * 8]);
      }
#pragma unroll
      for (int i = 0; i < 9; ++i) {  // B: 144 rows x 16 chunks
        int c = i * 256 + tid;
        int row = c >> 4;
        int l = (c & 15) ^ (row & 15);
        gld_lds16(Bb + (size_t)row * 2048 + k0 + l * 8, &Bsl[c * 8]);
      }
      __syncthreads();
#pragma unroll
      for (int h = 0; h < 4; ++h) {
        bf16x8 af;
        {
          int row = mw + l16;
          int p = (h * 4 + quad) ^ (row & 15);
          af = *(const bf16x8*)&Asl[row * 128 + p * 8];
        }
#pragma unroll
        for (int t = 0; t < 9; ++t) {
          int row = t * 16 + l16;
          int p = (h * 4 + quad) ^ (row & 15);
          bf16x8 bf = *(const bf16x8*)&Bsl[row * 128 + p * 8];
          acc[t] = __builtin_amdgcn_mfma_f32_16x16x32_bf16(af, bf, acc[t], 0, 0, 0);
        }
      }
      __syncthreads();
    }

    // C-tile -> LDS: Cl[dim * 68 + sample]  (dim 0..143 local, sample 0..63)
#pragma unroll
    for (int t = 0; t < 9; ++t) {
      int d = t * 16 + l16;
      int s0 = mw + quad * 4;
      *(f32x4*)&Cl[d * 68 + s0] = acc[t];
    }
    __syncthreads();

    const int jbase = yt * 16;
    const int k = mbase + lane;
#pragma unroll 1
    for (int pp = 0; pp < 4; ++pp) {
      int pl = wave * 4 + pp;  // local part 0..15
      int j = jbase + pl;
      float a[9];
#pragma unroll
      for (int i = 0; i < 9; ++i) a[i] = Cl[(pl * 9 + i) * 68 + lane];
#pragma unroll
      for (int i = 0; i < 9; ++i) omega[(size_t)(9 * j + i) * 2048 + k] = a[i];
      float E[9];
      expm3(a, E);
#pragma unroll
      for (int i = 0; i < 9; ++i) {
        rot[(size_t)(9 * j + i) * 2048 + k] = E[i];
        transf[(size_t)(12 * j + i) * 2048 + k] = E[i];
      }
    }
  } else {
    const int nt = yt - 8;
    const unsigned short* Ab = Ht + (size_t)mbase * 2048;
    const unsigned short* Bb = W3 + (size_t)nt * 128 * 2048;
    const int mw = (wave >> 1) * 32, nw = (wave & 1) * 64;
    f32x4 acc[2][4] = {};

    for (int k0 = 0; k0 < 2048; k0 += 128) {
#pragma unroll
      for (int i = 0; i < 4; ++i) {
        int c = i * 256 + tid;
        int row = c >> 4;
        int l = (c & 15) ^ (row & 15);
        gld_lds16(Ab + (size_t)row * 2048 + k0 + l * 8, &Asl[c * 8]);
      }
#pragma unroll
      for (int i = 0; i < 8; ++i) {
        int c = i * 256 + tid;
        int row = c >> 4;
        int l = (c & 15) ^ (row & 15);
        gld_lds16(Bb + (size_t)row * 2048 + k0 + l * 8, &Bsl[c * 8]);
      }
      __syncthreads();
#pragma unroll
      for (int h = 0; h < 4; ++h) {
        bf16x8 af[2], bfr[4];
#pragma unroll
        for (int t = 0; t < 2; ++t) {
          int row = mw + t * 16 + l16;
          int p = (h * 4 + quad) ^ (row & 15);
          af[t] = *(const bf16x8*)&Asl[row * 128 + p * 8];
        }
#pragma unroll
        for (int t = 0; t < 4; ++t) {
          int row = nw + t * 16 + l16;
          int p = (h * 4 + quad) ^ (row & 15);
          bfr[t] = *(const bf16x8*)&Bsl[row * 128 + p * 8];
        }
#pragma unroll
        for (int tm = 0; tm < 2; ++tm)
#pragma unroll
          for (int tn = 0; tn < 4; ++tn)
            acc[tm][tn] = __builtin_amdgcn_mfma_f32_16x16x32_bf16(af[tm], bfr[tn], acc[tm][tn], 0, 0, 0);
      }
      __syncthreads();
    }

    const int nbase = nt * 128 + nw;
#pragma unroll
    for (int tm = 0; tm < 2; ++tm) {
#pragma unroll
      for (int tn = 0; tn < 4; ++tn) {
        int n = nbase + tn * 16 + l16;       // 0..383
        int row0 = mbase + mw + tm * 16 + quad * 4;
        int j = n / 3, c = n % 3;
        *(f32x4*)&transl[(size_t)n * 2048 + row0] = acc[tm][tn];
        *(f32x4*)&transf[(size_t)(12 * j + 9 + c) * 2048 + row0] = acc[tm][tn];
      }
    }
  }
}

// ---------------------------------------------------------------------------
extern "C" void kernel_launch(void* const* d_in, const int* in_sizes, int n_in,
                              void* d_out, int out_size, void* d_ws, size_t ws_size,
                              hipStream_t stream) {
  const float* x   = (const float*)d_in[0];
  const float* Wo0 = (const float*)d_in[1];
  const float* Wo1 = (const float*)d_in[2];
  const float* Wo2 = (const float*)d_in[3];
  const float* Wo3 = (const float*)d_in[4];
  const float* Wt0 = (const float*)d_in[5];
  const float* Wt1 = (const float*)d_in[6];
  const float* Wt2 = (const float*)d_in[7];
  const float* Wt3 = (const float*)d_in[8];

  unsigned short* wb   = (unsigned short*)d_ws;
  unsigned short* wo0b = wb + 0;
  unsigned short* wo1b = wb + 262144;
  unsigned short* wo2b = wb + 4456448;
  unsigned short* wo3b = wb + 8650752;
  unsigned short* wt0b = wb + 11010048;
  unsigned short* wt1b = wb + 11272192;
  unsigned short* wt2b = wb + 15466496;
  unsigned short* wt3b = wb + 19660800;
  unsigned short* Xt   = wb + 20447232;  // 2048 x 128
  unsigned short* HoA  = Xt + 262144;    // 2048 x 2048 bf16 each
  unsigned short* HoB  = HoA + 4194304;
  unsigned short* HtA  = HoB + 4194304;
  unsigned short* HtB  = HtA + 4194304;
  // total ws use ~108 MB

  prep_k<<<10240, 256, 0, stream>>>(x, Wo0, Wo1, Wo2, Wo3, Wt0, Wt1, Wt2, Wt3, wb, Xt);

  // L0: K=128 -> single K-iteration
  gemm_tn<1><<<512, 256, 0, stream>>>(Xt, wo0b, HoA, 16, 2048,
                                      Xt, wt0b, HtA, 2048, 128);
  // L1
  gemm_tn<1><<<512, 256, 0, stream>>>(HoA, wo1b, HoB, 16, 2048,
                                      HtA, wt1b, HtB, 2048, 2048);
  // L2
  gemm_tn<1><<<512, 256, 0, stream>>>(HoB, wo2b, HoA, 16, 2048,
                                      HtB, wt2b, HtA, 2048, 2048);
  // L3 + expm + all outputs
  gemm_l3<<<dim3(32, 11), 256, 0, stream>>>(HoA, wo3b, HtA, wt3b, (float*)d_out);
}